// Round 5
// baseline (797.478 us; speedup 1.0000x reference)
//
#include <hip/hip_runtime.h>
#include <math.h>

#define HID   64
#define OUTC  40
#define CAP   64   // max in-degree bucket capacity (Poisson(16): P(overflow) ~ 1e-13)
#define ROWS  8    // rows (nodes) per wave in dense kernels

// ---------------- degree histogram ----------------
__global__ void deg_kernel(const int* __restrict__ dst, int* __restrict__ cnt, int E) {
    int e = blockIdx.x * blockDim.x + threadIdx.x;
    if (e < E) atomicAdd(&cnt[dst[e]], 1);
}

// dinv = rsqrt(deg+1); reset cnt for reuse as fill cursor
__global__ void dinv_kernel(int* __restrict__ cnt, float* __restrict__ dinv, int N) {
    int i = blockIdx.x * blockDim.x + threadIdx.x;
    if (i < N) {
        dinv[i] = rsqrtf((float)cnt[i] + 1.0f);
        cnt[i] = 0;
    }
}

// bucket fill: recs[dst][slot] = (src, enorm)
__global__ void fill_kernel(const int* __restrict__ src, const int* __restrict__ dst,
                            const float* __restrict__ dinv, int* __restrict__ cnt,
                            int2* __restrict__ recs, int E) {
    int e = blockIdx.x * blockDim.x + threadIdx.x;
    if (e < E) {
        int s = src[e], d = dst[e];
        float en = dinv[s] * dinv[d];
        int pos = atomicAdd(&cnt[d], 1);
        if (pos < CAP) recs[(size_t)d * CAP + pos] = make_int2(s, __float_as_int(en));
    }
}

// ---------------- dense transform: out[N,64] = X[N,CIN] @ W[CIN,64] ----------------
// lane = output col. ROWS nodes per wave -> 6250 waves (occupancy). W column in
// VGPRs, loaded in 64-row passes (keeps VGPR < 128). X rows staged in
// wave-PRIVATE LDS slice (no barriers anywhere), consumed as wave-uniform
// ds_read_b128 broadcasts. acc[ROWS] fully unrolled (static indexing).
template<int CIN>
__global__ __launch_bounds__(256) void xform_kernel(const float* __restrict__ X,
                                                    const float* __restrict__ W,
                                                    float* __restrict__ out, int N) {
    constexpr int RQ = CIN / 4;
    __shared__ float4 sh[4 * ROWS * RQ];
    int lane = threadIdx.x & 63;
    int w    = threadIdx.x >> 6;
    int row0 = (blockIdx.x * 4 + w) * ROWS;
    if (row0 >= N) return;
    int rows = N - row0; if (rows > ROWS) rows = ROWS;

    // stage this wave's rows (wave-private slice, no sync needed)
    float4* sl = sh + w * ROWS * RQ;
    const float4* xs = (const float4*)(X + (size_t)row0 * CIN);
    for (int i = lane; i < rows * RQ; i += 64) sl[i] = xs[i];

    float acc[ROWS];
    #pragma unroll
    for (int n = 0; n < ROWS; n++) acc[n] = 0.f;

    #pragma unroll
    for (int p = 0; p < CIN / 64; p++) {
        float wreg[64];
        #pragma unroll
        for (int kk = 0; kk < 64; kk++) wreg[kk] = W[((p * 64 + kk) << 6) + lane];
        #pragma unroll
        for (int n = 0; n < ROWS; n++) {
            float a0 = 0.f, a1 = 0.f, a2 = 0.f, a3 = 0.f;
            #pragma unroll
            for (int q = 0; q < 16; q++) {
                float4 xq = sl[n * RQ + (p << 4) + q];   // wave-uniform broadcast
                a0 = fmaf(xq.x, wreg[4 * q + 0], a0);
                a1 = fmaf(xq.y, wreg[4 * q + 1], a1);
                a2 = fmaf(xq.z, wreg[4 * q + 2], a2);
                a3 = fmaf(xq.w, wreg[4 * q + 3], a3);
            }
            acc[n] += (a0 + a1) + (a2 + a3);
        }
    }

    float* outp = out + ((size_t)row0 << 6) + lane;
    #pragma unroll
    for (int n = 0; n < ROWS; n++)
        if (n < rows) outp[(size_t)n << 6] = acc[n];
}

// ---------------- gather-aggregate + self-loop + bias (+ LN + ReLU) ----------------
// Edge loop padded to multiples of 8: always 8 loads in flight, no scalar tail.
// Masked lanes broadcast (s=0, e=0) -> row-0 loads are L1-hot and contribute 0.
template<bool LN>
__global__ void conv_kernel(const float* __restrict__ hw, const int2* __restrict__ recs,
                            const int* __restrict__ cnt, const float* __restrict__ dinv,
                            const float* __restrict__ b, const float* __restrict__ g,
                            const float* __restrict__ be, float* __restrict__ out, int N) {
    int lane = threadIdx.x & 63;
    int row  = (blockIdx.x << 2) + (threadIdx.x >> 6);
    if (row >= N) return;

    int c = cnt[row];
    if (c > CAP) c = CAP;

    int2 myrec = make_int2(0, 0);   // masked slots: s=0, e=0
    if (lane < c) myrec = recs[(size_t)row * CAP + lane];

    float di    = dinv[row];
    float selfv = hw[((size_t)row << 6) + lane];   // issue early

    float a0 = 0.f, a1 = 0.f, a2 = 0.f, a3 = 0.f;
    int kmax = (c + 7) & ~7;
    for (int k = 0; k < kmax; k += 8) {
        int   s[8]; float e[8], v[8];
        #pragma unroll
        for (int u = 0; u < 8; u++) {
            s[u] = __shfl(myrec.x, k + u);
            e[u] = __shfl(__int_as_float(myrec.y), k + u);
        }
        #pragma unroll
        for (int u = 0; u < 8; u++) v[u] = hw[((size_t)s[u] << 6) + lane];
        a0 = fmaf(e[0], v[0], a0); a1 = fmaf(e[1], v[1], a1);
        a2 = fmaf(e[2], v[2], a2); a3 = fmaf(e[3], v[3], a3);
        a0 = fmaf(e[4], v[4], a0); a1 = fmaf(e[5], v[5], a1);
        a2 = fmaf(e[6], v[6], a2); a3 = fmaf(e[7], v[7], a3);
    }
    float acc = (a0 + a1) + (a2 + a3);
    acc = fmaf(di * di, selfv, acc) + b[lane];

    if (LN) {
        float s = acc;
        #pragma unroll
        for (int o = 32; o; o >>= 1) s += __shfl_xor(s, o);
        float mu = s * (1.f / 64.f);
        float d0 = acc - mu;
        float v  = d0 * d0;
        #pragma unroll
        for (int o = 32; o; o >>= 1) v += __shfl_xor(v, o);
        v *= (1.f / 64.f);
        acc = d0 * rsqrtf(v + 1e-5f) * g[lane] + be[lane];
        acc = fmaxf(acc, 0.f);
    }
    out[((size_t)row << 6) + lane] = acc;
}

// ---------------- MLP (64->64 relu ->40) + softmax ----------------
// lane = output col, ROWS nodes/wave, wave-private LDS (no block barriers).
// h2 exchanged through wave-private slice (same-wave DS is in-order).
__global__ __launch_bounds__(256) void mlp_kernel(const float* __restrict__ h,
                           const float* __restrict__ M1, const float* __restrict__ mb1,
                           const float* __restrict__ M2, const float* __restrict__ mb2,
                           float* __restrict__ out, int N) {
    __shared__ float4 sh[4 * ROWS * 16];
    __shared__ float4 h2s[4 * 16];
    int lane = threadIdx.x & 63;
    int w    = threadIdx.x >> 6;
    int row0 = (blockIdx.x * 4 + w) * ROWS;
    if (row0 >= N) return;
    int rows = N - row0; if (rows > ROWS) rows = ROWS;

    float m1reg[64], m2reg[64];
    #pragma unroll
    for (int k = 0; k < 64; k++) m1reg[k] = M1[(k << 6) + lane];
    #pragma unroll
    for (int k = 0; k < 64; k++) m2reg[k] = (lane < OUTC) ? M2[k * OUTC + lane] : 0.f;
    float b1v = mb1[lane];
    float b2v = (lane < OUTC) ? mb2[lane] : 0.f;

    float4* sl = sh + w * ROWS * 16;
    const float4* hs = (const float4*)(h + ((size_t)row0 << 6));
    for (int i = lane; i < rows * 16; i += 64) sl[i] = hs[i];

    float4* hb = h2s + w * 16;
    float*  hbf = (float*)hb;
    for (int n = 0; n < rows; n++) {
        // matvec M1 (64x64): wave-uniform b128 broadcasts x VGPR column
        float a0 = 0.f, a1 = 0.f, a2 = 0.f, a3 = 0.f;
        #pragma unroll
        for (int q = 0; q < 16; q++) {
            float4 xq = sl[n * 16 + q];
            a0 = fmaf(xq.x, m1reg[4 * q + 0], a0);
            a1 = fmaf(xq.y, m1reg[4 * q + 1], a1);
            a2 = fmaf(xq.z, m1reg[4 * q + 2], a2);
            a3 = fmaf(xq.w, m1reg[4 * q + 3], a3);
        }
        float h2 = fmaxf((a0 + a1) + (a2 + a3) + b1v, 0.f);

        hbf[lane] = h2;                       // wave-private exchange
        __builtin_amdgcn_wave_barrier();      // keep compiler from reordering

        a0 = a1 = a2 = a3 = 0.f;
        #pragma unroll
        for (int q = 0; q < 16; q++) {
            float4 xq = hb[q];
            a0 = fmaf(xq.x, m2reg[4 * q + 0], a0);
            a1 = fmaf(xq.y, m2reg[4 * q + 1], a1);
            a2 = fmaf(xq.z, m2reg[4 * q + 2], a2);
            a3 = fmaf(xq.w, m2reg[4 * q + 3], a3);
        }
        float o = (a0 + a1) + (a2 + a3) + b2v;
        __builtin_amdgcn_wave_barrier();      // reads done before next write

        float logit = (lane < OUTC) ? o : -INFINITY;
        float mx = logit;
        #pragma unroll
        for (int s = 32; s; s >>= 1) mx = fmaxf(mx, __shfl_xor(mx, s));
        float e = (lane < OUTC) ? __expf(logit - mx) : 0.f;
        float sum = e;
        #pragma unroll
        for (int s = 32; s; s >>= 1) sum += __shfl_xor(sum, s);
        if (lane < OUTC) out[(size_t)(row0 + n) * OUTC + lane] = e / sum;
    }
}

extern "C" void kernel_launch(void* const* d_in, const int* in_sizes, int n_in,
                              void* d_out, int out_size, void* d_ws, size_t ws_size,
                              hipStream_t stream) {
    const float* x   = (const float*)d_in[0];
    const int*   ei  = (const int*)  d_in[1];
    const float* W1  = (const float*)d_in[2];
    const float* b1  = (const float*)d_in[3];
    const float* W2  = (const float*)d_in[4];
    const float* b2  = (const float*)d_in[5];
    const float* W3  = (const float*)d_in[6];
    const float* b3  = (const float*)d_in[7];
    const float* g1  = (const float*)d_in[8];
    const float* be1 = (const float*)d_in[9];
    const float* g2  = (const float*)d_in[10];
    const float* be2 = (const float*)d_in[11];
    const float* M1  = (const float*)d_in[12];
    const float* mb1 = (const float*)d_in[13];
    const float* M2  = (const float*)d_in[14];
    const float* mb2 = (const float*)d_in[15];

    const int IN_C = 128;
    int N = in_sizes[0] / IN_C;
    int E = in_sizes[1] / 2;
    const int* src = ei;
    const int* dst = ei + E;

    // workspace carve-up
    char* ws = (char*)d_ws;
    size_t off = 0;
    auto carve = [&](size_t bytes) -> void* {
        void* p = ws + off;
        off = (off + bytes + 255) & ~(size_t)255;
        return p;
    };
    int*   cnt  = (int*)  carve((size_t)N * sizeof(int));
    float* dinv = (float*)carve((size_t)N * sizeof(float));
    int2*  recs = (int2*) carve((size_t)N * CAP * sizeof(int2));
    float* HW   = (float*)carve((size_t)N * HID * sizeof(float));
    float* H    = (float*)carve((size_t)N * HID * sizeof(float));

    hipMemsetAsync(cnt, 0, (size_t)N * sizeof(int), stream);

    int eb = (E + 255) / 256;
    int nb = (N + 255) / 256;
    int rb = (N + 3) / 4;                 // conv: one wave per node, 4 waves/block
    int xb = (N + 4 * ROWS - 1) / (4 * ROWS);  // xform/mlp: 4 waves x ROWS nodes

    deg_kernel <<<eb, 256, 0, stream>>>(dst, cnt, E);
    dinv_kernel<<<nb, 256, 0, stream>>>(cnt, dinv, N);
    fill_kernel<<<eb, 256, 0, stream>>>(src, dst, dinv, cnt, recs, E);

    // layer 1
    xform_kernel<128><<<xb, 256, 0, stream>>>(x, W1, HW, N);
    conv_kernel<true><<<rb, 256, 0, stream>>>(HW, recs, cnt, dinv, b1, g1, be1, H, N);
    // layer 2
    xform_kernel<64><<<xb, 256, 0, stream>>>(H, W2, HW, N);
    conv_kernel<true><<<rb, 256, 0, stream>>>(HW, recs, cnt, dinv, b2, g2, be2, H, N);
    // layer 3 (no LN/ReLU)
    xform_kernel<64><<<xb, 256, 0, stream>>>(H, W3, HW, N);
    conv_kernel<false><<<rb, 256, 0, stream>>>(HW, recs, cnt, dinv, b3, nullptr, nullptr, H, N);

    // MLP + softmax
    mlp_kernel<<<xb, 256, 0, stream>>>(H, M1, mb1, M2, mb2, (float*)d_out, N);
}

// Round 6
// 258.654 us; speedup vs baseline: 3.0832x; 3.0832x over previous
//
#include <hip/hip_runtime.h>
#include <math.h>

#define HID   64
#define OUTC  40
#define CAP   64   // max in-degree bucket capacity (Poisson(16): P(overflow) ~ 1e-13)

// ---------------- degree histogram ----------------
__global__ void deg_kernel(const int* __restrict__ dst, int* __restrict__ cnt, int E) {
    int e = blockIdx.x * blockDim.x + threadIdx.x;
    if (e < E) atomicAdd(&cnt[dst[e]], 1);
}

// dinv = rsqrt(deg+1); reset cnt for reuse as fill cursor
__global__ void dinv_kernel(int* __restrict__ cnt, float* __restrict__ dinv, int N) {
    int i = blockIdx.x * blockDim.x + threadIdx.x;
    if (i < N) {
        dinv[i] = rsqrtf((float)cnt[i] + 1.0f);
        cnt[i] = 0;
    }
}

// bucket fill: recs[dst][slot] = (src, enorm)
__global__ void fill_kernel(const int* __restrict__ src, const int* __restrict__ dst,
                            const float* __restrict__ dinv, int* __restrict__ cnt,
                            int2* __restrict__ recs, int E) {
    int e = blockIdx.x * blockDim.x + threadIdx.x;
    if (e < E) {
        int s = src[e], d = dst[e];
        float en = dinv[s] * dinv[d];
        int pos = atomicAdd(&cnt[d], 1);
        if (pos < CAP) recs[(size_t)d * CAP + pos] = make_int2(s, __float_as_int(en));
    }
}

#define FMA16(acc, a, b) \
    acc[0][0] = fmaf(a.x, b.x, acc[0][0]); acc[0][1] = fmaf(a.x, b.y, acc[0][1]); \
    acc[0][2] = fmaf(a.x, b.z, acc[0][2]); acc[0][3] = fmaf(a.x, b.w, acc[0][3]); \
    acc[1][0] = fmaf(a.y, b.x, acc[1][0]); acc[1][1] = fmaf(a.y, b.y, acc[1][1]); \
    acc[1][2] = fmaf(a.y, b.z, acc[1][2]); acc[1][3] = fmaf(a.y, b.w, acc[1][3]); \
    acc[2][0] = fmaf(a.z, b.x, acc[2][0]); acc[2][1] = fmaf(a.z, b.y, acc[2][1]); \
    acc[2][2] = fmaf(a.z, b.z, acc[2][2]); acc[2][3] = fmaf(a.z, b.w, acc[2][3]); \
    acc[3][0] = fmaf(a.w, b.x, acc[3][0]); acc[3][1] = fmaf(a.w, b.y, acc[3][1]); \
    acc[3][2] = fmaf(a.w, b.z, acc[3][2]); acc[3][3] = fmaf(a.w, b.w, acc[3][3]);

// ---------------- dense transform: out[N,64] = X[N,CIN] @ W[CIN,64] ----------------
// Canonical tiled GEMM: 64x64 tile per 256-thread block, 4x4 register micro-tile
// per thread (16 acc + 8 operand VGPRs -- cannot spill). Operands staged k-major
// in LDS (stride 68: 16B-aligned b128, 2-way banks = free). One barrier total.
template<int CIN>
__global__ __launch_bounds__(256) void xform_kernel(const float* __restrict__ X,
                                                    const float* __restrict__ W,
                                                    float* __restrict__ out, int N) {
    __shared__ float Xs[CIN][68];   // k-major: Xs[k][row]
    __shared__ float Ws[CIN][68];   // k-major: Ws[k][col]
    int tid = threadIdx.x;
    int base = blockIdx.x << 6;
    int rows = N - base; if (rows > 64) rows = 64;

    {   // stage W (coalesced 256B per k-row)
        int k = tid >> 4, c = (tid & 15) << 2;
        #pragma unroll
        for (int k0 = 0; k0 < CIN; k0 += 16) {
            float4 wv = *(const float4*)(W + (size_t)((k0 + k) << 6) + c);
            *(float4*)&Ws[k0 + k][c] = wv;
        }
    }
    {   // stage X transposed to k-major (tail rows clamp to row 0: finite, unused)
        int r = tid >> 2, q = (tid & 3) << 2;
        int rc = r < rows ? r : 0;
        const float* xp = X + (size_t)(base + rc) * CIN + q;
        #pragma unroll
        for (int k0 = 0; k0 < CIN; k0 += 16) {
            float4 xv = *(const float4*)(xp + k0);
            Xs[k0 + q + 0][r] = xv.x;
            Xs[k0 + q + 1][r] = xv.y;
            Xs[k0 + q + 2][r] = xv.z;
            Xs[k0 + q + 3][r] = xv.w;
        }
    }
    __syncthreads();

    int tx = tid & 15, ty = tid >> 4;
    float acc[4][4] = {};
    #pragma unroll 4
    for (int k = 0; k < CIN; k++) {
        float4 a = *(const float4*)&Xs[k][ty << 2];
        float4 b = *(const float4*)&Ws[k][tx << 2];
        FMA16(acc, a, b)
    }
    #pragma unroll
    for (int rr = 0; rr < 4; rr++) {
        int row = (ty << 2) + rr;
        if (row < rows)
            *(float4*)(out + ((size_t)(base + row) << 6) + (tx << 2)) =
                make_float4(acc[rr][0], acc[rr][1], acc[rr][2], acc[rr][3]);
    }
}

// ---------------- gather-aggregate + self-loop + bias (+ LN + ReLU) ----------------
// Edge loop padded to multiples of 8: 8 loads in flight, no scalar tail.
template<bool LN>
__global__ void conv_kernel(const float* __restrict__ hw, const int2* __restrict__ recs,
                            const int* __restrict__ cnt, const float* __restrict__ dinv,
                            const float* __restrict__ b, const float* __restrict__ g,
                            const float* __restrict__ be, float* __restrict__ out, int N) {
    int lane = threadIdx.x & 63;
    int row  = (blockIdx.x << 2) + (threadIdx.x >> 6);
    if (row >= N) return;

    int c = cnt[row];
    if (c > CAP) c = CAP;

    int2 myrec = make_int2(0, 0);   // masked slots: s=0, e=0
    if (lane < c) myrec = recs[(size_t)row * CAP + lane];

    float di    = dinv[row];
    float selfv = hw[((size_t)row << 6) + lane];   // issue early

    float a0 = 0.f, a1 = 0.f, a2 = 0.f, a3 = 0.f;
    int kmax = (c + 7) & ~7;
    for (int k = 0; k < kmax; k += 8) {
        int   s[8]; float e[8], v[8];
        #pragma unroll
        for (int u = 0; u < 8; u++) {
            s[u] = __shfl(myrec.x, k + u);
            e[u] = __shfl(__int_as_float(myrec.y), k + u);
        }
        #pragma unroll
        for (int u = 0; u < 8; u++) v[u] = hw[((size_t)s[u] << 6) + lane];
        a0 = fmaf(e[0], v[0], a0); a1 = fmaf(e[1], v[1], a1);
        a2 = fmaf(e[2], v[2], a2); a3 = fmaf(e[3], v[3], a3);
        a0 = fmaf(e[4], v[4], a0); a1 = fmaf(e[5], v[5], a1);
        a2 = fmaf(e[6], v[6], a2); a3 = fmaf(e[7], v[7], a3);
    }
    float acc = (a0 + a1) + (a2 + a3);
    acc = fmaf(di * di, selfv, acc) + b[lane];

    if (LN) {
        float s = acc;
        #pragma unroll
        for (int o = 32; o; o >>= 1) s += __shfl_xor(s, o);
        float mu = s * (1.f / 64.f);
        float d0 = acc - mu;
        float v  = d0 * d0;
        #pragma unroll
        for (int o = 32; o; o >>= 1) v += __shfl_xor(v, o);
        v *= (1.f / 64.f);
        acc = d0 * rsqrtf(v + 1e-5f) * g[lane] + be[lane];
        acc = fmaxf(acc, 0.f);
    }
    out[((size_t)row << 6) + lane] = acc;
}

// ---------------- MLP (64->64 relu ->40) + softmax ----------------
// Same tiled-GEMM skeleton twice; softmax via shfl_xor over the tx dimension.
__global__ __launch_bounds__(256) void mlp_kernel(const float* __restrict__ h,
                           const float* __restrict__ M1, const float* __restrict__ mb1,
                           const float* __restrict__ M2, const float* __restrict__ mb2,
                           float* __restrict__ out, int N) {
    __shared__ float Hs [64][68];
    __shared__ float W1s[64][68];
    __shared__ float H2s[64][68];
    __shared__ float W2s[64][44];
    int tid = threadIdx.x;
    int base = blockIdx.x << 6;
    int rows = N - base; if (rows > 64) rows = 64;

    {   // stage M1
        int k = tid >> 4, c = (tid & 15) << 2;
        #pragma unroll
        for (int k0 = 0; k0 < 64; k0 += 16) {
            float4 wv = *(const float4*)(M1 + (size_t)((k0 + k) << 6) + c);
            *(float4*)&W1s[k0 + k][c] = wv;
        }
    }
    for (int i = tid; i < 64 * OUTC; i += 256)   // stage M2 [64][40]
        W2s[i / OUTC][i % OUTC] = M2[i];
    {   // stage h transposed
        int r = tid >> 2, q = (tid & 3) << 2;
        int rc = r < rows ? r : 0;
        const float* xp = h + (((size_t)(base + rc)) << 6) + q;
        #pragma unroll
        for (int k0 = 0; k0 < 64; k0 += 16) {
            float4 xv = *(const float4*)(xp + k0);
            Hs[k0 + q + 0][r] = xv.x;
            Hs[k0 + q + 1][r] = xv.y;
            Hs[k0 + q + 2][r] = xv.z;
            Hs[k0 + q + 3][r] = xv.w;
        }
    }
    __syncthreads();

    int tx = tid & 15, ty = tid >> 4;

    // GEMM1: H @ M1
    float acc[4][4] = {};
    #pragma unroll 4
    for (int k = 0; k < 64; k++) {
        float4 a = *(const float4*)&Hs[k][ty << 2];
        float4 b = *(const float4*)&W1s[k][tx << 2];
        FMA16(acc, a, b)
    }
    // bias + relu, write transposed (k-major) for GEMM2
    float4 b1v = *(const float4*)(mb1 + (tx << 2));
    #pragma unroll
    for (int cc = 0; cc < 4; cc++) {
        float bc = cc == 0 ? b1v.x : cc == 1 ? b1v.y : cc == 2 ? b1v.z : b1v.w;
        #pragma unroll
        for (int rr = 0; rr < 4; rr++)
            H2s[(tx << 2) + cc][(ty << 2) + rr] = fmaxf(acc[rr][cc] + bc, 0.f);
    }
    __syncthreads();

    // GEMM2: H2 @ M2 (40 cols: tx<10 active)
    int bx = (tx < 10) ? (tx << 2) : 0;
    float acc2[4][4] = {};
    #pragma unroll 4
    for (int k = 0; k < 64; k++) {
        float4 a = *(const float4*)&H2s[k][ty << 2];
        float4 b = *(const float4*)&W2s[k][bx];
        FMA16(acc2, a, b)
    }
    float4 b2v = *(const float4*)(mb2 + bx);

    // softmax across the 40 cols (10 tx-threads x 4 cc) per row
    #pragma unroll
    for (int rr = 0; rr < 4; rr++) {
        float v0 = acc2[rr][0] + b2v.x, v1 = acc2[rr][1] + b2v.y;
        float v2 = acc2[rr][2] + b2v.z, v3 = acc2[rr][3] + b2v.w;
        float m = fmaxf(fmaxf(v0, v1), fmaxf(v2, v3));
        if (tx >= 10) m = -1e30f;
        #pragma unroll
        for (int s = 1; s < 16; s <<= 1) m = fmaxf(m, __shfl_xor(m, s));
        float e0 = __expf(v0 - m), e1 = __expf(v1 - m);
        float e2 = __expf(v2 - m), e3 = __expf(v3 - m);
        float sum = (tx < 10) ? (e0 + e1) + (e2 + e3) : 0.f;
        #pragma unroll
        for (int s = 1; s < 16; s <<= 1) sum += __shfl_xor(sum, s);
        float inv = 1.f / sum;
        int row = (ty << 2) + rr;
        if (tx < 10 && row < rows)
            *(float4*)(out + (size_t)(base + row) * OUTC + bx) =
                make_float4(e0 * inv, e1 * inv, e2 * inv, e3 * inv);
    }
}

extern "C" void kernel_launch(void* const* d_in, const int* in_sizes, int n_in,
                              void* d_out, int out_size, void* d_ws, size_t ws_size,
                              hipStream_t stream) {
    const float* x   = (const float*)d_in[0];
    const int*   ei  = (const int*)  d_in[1];
    const float* W1  = (const float*)d_in[2];
    const float* b1  = (const float*)d_in[3];
    const float* W2  = (const float*)d_in[4];
    const float* b2  = (const float*)d_in[5];
    const float* W3  = (const float*)d_in[6];
    const float* b3  = (const float*)d_in[7];
    const float* g1  = (const float*)d_in[8];
    const float* be1 = (const float*)d_in[9];
    const float* g2  = (const float*)d_in[10];
    const float* be2 = (const float*)d_in[11];
    const float* M1  = (const float*)d_in[12];
    const float* mb1 = (const float*)d_in[13];
    const float* M2  = (const float*)d_in[14];
    const float* mb2 = (const float*)d_in[15];

    const int IN_C = 128;
    int N = in_sizes[0] / IN_C;
    int E = in_sizes[1] / 2;
    const int* src = ei;
    const int* dst = ei + E;

    // workspace carve-up
    char* ws = (char*)d_ws;
    size_t off = 0;
    auto carve = [&](size_t bytes) -> void* {
        void* p = ws + off;
        off = (off + bytes + 255) & ~(size_t)255;
        return p;
    };
    int*   cnt  = (int*)  carve((size_t)N * sizeof(int));
    float* dinv = (float*)carve((size_t)N * sizeof(float));
    int2*  recs = (int2*) carve((size_t)N * CAP * sizeof(int2));
    float* HW   = (float*)carve((size_t)N * HID * sizeof(float));
    float* H    = (float*)carve((size_t)N * HID * sizeof(float));

    hipMemsetAsync(cnt, 0, (size_t)N * sizeof(int), stream);

    int eb = (E + 255) / 256;
    int nb = (N + 255) / 256;
    int rb = (N + 3) / 4;    // conv: one wave per node, 4 waves/block
    int tb = (N + 63) / 64;  // xform/mlp: 64-row tile per 256-thread block

    deg_kernel <<<eb, 256, 0, stream>>>(dst, cnt, E);
    dinv_kernel<<<nb, 256, 0, stream>>>(cnt, dinv, N);
    fill_kernel<<<eb, 256, 0, stream>>>(src, dst, dinv, cnt, recs, E);

    // layer 1
    xform_kernel<128><<<tb, 256, 0, stream>>>(x, W1, HW, N);
    conv_kernel<true><<<rb, 256, 0, stream>>>(HW, recs, cnt, dinv, b1, g1, be1, H, N);
    // layer 2
    xform_kernel<64><<<tb, 256, 0, stream>>>(H, W2, HW, N);
    conv_kernel<true><<<rb, 256, 0, stream>>>(HW, recs, cnt, dinv, b2, g2, be2, H, N);
    // layer 3 (no LN/ReLU)
    xform_kernel<64><<<tb, 256, 0, stream>>>(H, W3, HW, N);
    conv_kernel<false><<<rb, 256, 0, stream>>>(HW, recs, cnt, dinv, b3, nullptr, nullptr, H, N);

    // MLP + softmax
    mlp_kernel<<<tb, 256, 0, stream>>>(H, M1, mb1, M2, mb2, (float*)d_out, N);
}

// Round 7
// 248.048 us; speedup vs baseline: 3.2150x; 1.0428x over previous
//
#include <hip/hip_runtime.h>
#include <math.h>

#define HID   64
#define OUTC  40
#define CAP   64   // max in-degree bucket capacity (Poisson(16): P(overflow) ~ 1e-13)

// ---------------- fused degree-count + bucket fill (single edge pass) ----------------
// After this kernel cnt[d] = full in-degree (may exceed CAP; conv clamps).
__global__ void fill_kernel(const int* __restrict__ src, const int* __restrict__ dst,
                            int* __restrict__ cnt, int* __restrict__ recs, int E) {
    int e = blockIdx.x * blockDim.x + threadIdx.x;
    if (e < E) {
        int d = dst[e];
        int pos = atomicAdd(&cnt[d], 1);
        if (pos < CAP) recs[(size_t)d * CAP + pos] = src[e];
    }
}

// dinv = rsqrt(deg+1)
__global__ void dinv_kernel(const int* __restrict__ cnt, float* __restrict__ dinv, int N) {
    int i = blockIdx.x * blockDim.x + threadIdx.x;
    if (i < N) dinv[i] = rsqrtf((float)cnt[i] + 1.0f);
}

#define FMA16(acc, a, b) \
    acc[0][0] = fmaf(a.x, b.x, acc[0][0]); acc[0][1] = fmaf(a.x, b.y, acc[0][1]); \
    acc[0][2] = fmaf(a.x, b.z, acc[0][2]); acc[0][3] = fmaf(a.x, b.w, acc[0][3]); \
    acc[1][0] = fmaf(a.y, b.x, acc[1][0]); acc[1][1] = fmaf(a.y, b.y, acc[1][1]); \
    acc[1][2] = fmaf(a.y, b.z, acc[1][2]); acc[1][3] = fmaf(a.y, b.w, acc[1][3]); \
    acc[2][0] = fmaf(a.z, b.x, acc[2][0]); acc[2][1] = fmaf(a.z, b.y, acc[2][1]); \
    acc[2][2] = fmaf(a.z, b.z, acc[2][2]); acc[2][3] = fmaf(a.z, b.w, acc[2][3]); \
    acc[3][0] = fmaf(a.w, b.x, acc[3][0]); acc[3][1] = fmaf(a.w, b.y, acc[3][1]); \
    acc[3][2] = fmaf(a.w, b.z, acc[3][2]); acc[3][3] = fmaf(a.w, b.w, acc[3][3]);

// ---------------- dense transform: out[N,64] = X[N,CIN] @ W[CIN,64] ----------------
// Canonical tiled GEMM: 64x64 tile / 256 threads, 4x4 micro-tile (no spill).
template<int CIN>
__global__ __launch_bounds__(256) void xform_kernel(const float* __restrict__ X,
                                                    const float* __restrict__ W,
                                                    float* __restrict__ out, int N) {
    __shared__ float Xs[CIN][68];   // k-major: Xs[k][row]
    __shared__ float Ws[CIN][68];   // k-major: Ws[k][col]
    int tid = threadIdx.x;
    int base = blockIdx.x << 6;
    int rows = N - base; if (rows > 64) rows = 64;

    {   // stage W
        int k = tid >> 4, c = (tid & 15) << 2;
        #pragma unroll
        for (int k0 = 0; k0 < CIN; k0 += 16) {
            float4 wv = *(const float4*)(W + (size_t)((k0 + k) << 6) + c);
            *(float4*)&Ws[k0 + k][c] = wv;
        }
    }
    {   // stage X transposed to k-major
        int r = tid >> 2, q = (tid & 3) << 2;
        int rc = r < rows ? r : 0;
        const float* xp = X + (size_t)(base + rc) * CIN + q;
        #pragma unroll
        for (int k0 = 0; k0 < CIN; k0 += 16) {
            float4 xv = *(const float4*)(xp + k0);
            Xs[k0 + q + 0][r] = xv.x;
            Xs[k0 + q + 1][r] = xv.y;
            Xs[k0 + q + 2][r] = xv.z;
            Xs[k0 + q + 3][r] = xv.w;
        }
    }
    __syncthreads();

    int tx = tid & 15, ty = tid >> 4;
    float acc[4][4] = {};
    #pragma unroll 4
    for (int k = 0; k < CIN; k++) {
        float4 a = *(const float4*)&Xs[k][ty << 2];
        float4 b = *(const float4*)&Ws[k][tx << 2];
        FMA16(acc, a, b)
    }
    #pragma unroll
    for (int rr = 0; rr < 4; rr++) {
        int row = (ty << 2) + rr;
        if (row < rows)
            *(float4*)(out + ((size_t)(base + row) << 6) + (tx << 2)) =
                make_float4(acc[rr][0], acc[rr][1], acc[rr][2], acc[rr][3]);
    }
}

// ---------------- gather-aggregate + self-loop + bias (+ LN + ReLU) ----------------
// recs holds src only; dinv[s] gathered here (L2-hot 200KB). dinv[row] factors
// out of the edge sum: acc = di * sum(ds_k * hw[s_k]) + di^2*self + b.
template<bool LN>
__global__ void conv_kernel(const float* __restrict__ hw, const int* __restrict__ recs,
                            const int* __restrict__ cnt, const float* __restrict__ dinv,
                            const float* __restrict__ b, const float* __restrict__ g,
                            const float* __restrict__ be, float* __restrict__ out, int N) {
    int lane = threadIdx.x & 63;
    int row  = (blockIdx.x << 2) + (threadIdx.x >> 6);
    if (row >= N) return;

    int c = cnt[row];
    if (c > CAP) c = CAP;

    int   s_l = 0; float ds_l = 0.f;   // masked slots: s=0, ds=0 -> contribute 0
    if (lane < c) { s_l = recs[(size_t)row * CAP + lane]; ds_l = dinv[s_l]; }

    float di    = dinv[row];
    float selfv = hw[((size_t)row << 6) + lane];   // issue early

    float a0 = 0.f, a1 = 0.f, a2 = 0.f, a3 = 0.f;
    int kmax = (c + 7) & ~7;
    for (int k = 0; k < kmax; k += 8) {
        int   s[8]; float e[8], v[8];
        #pragma unroll
        for (int u = 0; u < 8; u++) {
            s[u] = __shfl(s_l, k + u);
            e[u] = __shfl(ds_l, k + u);
        }
        #pragma unroll
        for (int u = 0; u < 8; u++) v[u] = hw[((size_t)s[u] << 6) + lane];
        a0 = fmaf(e[0], v[0], a0); a1 = fmaf(e[1], v[1], a1);
        a2 = fmaf(e[2], v[2], a2); a3 = fmaf(e[3], v[3], a3);
        a0 = fmaf(e[4], v[4], a0); a1 = fmaf(e[5], v[5], a1);
        a2 = fmaf(e[6], v[6], a2); a3 = fmaf(e[7], v[7], a3);
    }
    float acc = ((a0 + a1) + (a2 + a3)) * di;
    acc = fmaf(di * di, selfv, acc) + b[lane];

    if (LN) {
        float s = acc;
        #pragma unroll
        for (int o = 32; o; o >>= 1) s += __shfl_xor(s, o);
        float mu = s * (1.f / 64.f);
        float d0 = acc - mu;
        float v  = d0 * d0;
        #pragma unroll
        for (int o = 32; o; o >>= 1) v += __shfl_xor(v, o);
        v *= (1.f / 64.f);
        acc = d0 * rsqrtf(v + 1e-5f) * g[lane] + be[lane];
        acc = fmaxf(acc, 0.f);
    }
    out[((size_t)row << 6) + lane] = acc;
}

// ---------------- fused conv3 (no LN) + MLP + softmax ----------------
// Phase A: each of 4 waves gathers 16 rows directly into k-major LDS.
// Phase B/C: the proven tiled-GEMM pair; H2 reuses the Hs buffer (46KB LDS).
__global__ __launch_bounds__(256) void convmlp_kernel(
        const float* __restrict__ hw, const int* __restrict__ recs,
        const int* __restrict__ cnt, const float* __restrict__ dinv,
        const float* __restrict__ b3,
        const float* __restrict__ M1, const float* __restrict__ mb1,
        const float* __restrict__ M2, const float* __restrict__ mb2,
        float* __restrict__ out, int N) {
    __shared__ float Hs [64][68];
    __shared__ float W1s[64][68];
    __shared__ float W2s[64][44];
    int tid = threadIdx.x, lane = tid & 63, w = tid >> 6;
    int base = blockIdx.x << 6;
    int rows = N - base; if (rows > 64) rows = 64;

    {   // stage M1 (k-major as stored)
        int k = tid >> 4, c = (tid & 15) << 2;
        #pragma unroll
        for (int k0 = 0; k0 < 64; k0 += 16) {
            float4 wv = *(const float4*)(M1 + (size_t)((k0 + k) << 6) + c);
            *(float4*)&W1s[k0 + k][c] = wv;
        }
    }
    for (int i = tid; i < 64 * OUTC; i += 256)
        W2s[i / OUTC][i % OUTC] = M2[i];

    // phase A: conv gather, one wave per 16 rows, result -> Hs[feat][rowidx]
    float b3v = b3[lane];
    for (int rr = 0; rr < 16; rr++) {
        int idx = w * 16 + rr;
        int row = base + idx;
        if (row >= N) { Hs[lane][idx] = 0.f; continue; }
        int c = cnt[row];
        if (c > CAP) c = CAP;
        int   s_l = 0; float ds_l = 0.f;
        if (lane < c) { s_l = recs[(size_t)row * CAP + lane]; ds_l = dinv[s_l]; }
        float di    = dinv[row];
        float selfv = hw[((size_t)row << 6) + lane];
        float a0 = 0.f, a1 = 0.f, a2 = 0.f, a3 = 0.f;
        int kmax = (c + 7) & ~7;
        for (int k = 0; k < kmax; k += 8) {
            int   s[8]; float e[8], v[8];
            #pragma unroll
            for (int u = 0; u < 8; u++) {
                s[u] = __shfl(s_l, k + u);
                e[u] = __shfl(ds_l, k + u);
            }
            #pragma unroll
            for (int u = 0; u < 8; u++) v[u] = hw[((size_t)s[u] << 6) + lane];
            a0 = fmaf(e[0], v[0], a0); a1 = fmaf(e[1], v[1], a1);
            a2 = fmaf(e[2], v[2], a2); a3 = fmaf(e[3], v[3], a3);
            a0 = fmaf(e[4], v[4], a0); a1 = fmaf(e[5], v[5], a1);
            a2 = fmaf(e[6], v[6], a2); a3 = fmaf(e[7], v[7], a3);
        }
        float acc = ((a0 + a1) + (a2 + a3)) * di;
        acc = fmaf(di * di, selfv, acc) + b3v;
        Hs[lane][idx] = acc;    // k-major for GEMM1
    }
    __syncthreads();

    int tx = tid & 15, ty = tid >> 4;

    // GEMM1: H @ M1
    float acc[4][4] = {};
    #pragma unroll 4
    for (int k = 0; k < 64; k++) {
        float4 a = *(const float4*)&Hs[k][ty << 2];
        float4 b = *(const float4*)&W1s[k][tx << 2];
        FMA16(acc, a, b)
    }
    float4 b1v = *(const float4*)(mb1 + (tx << 2));
    __syncthreads();   // all GEMM1 reads of Hs complete before overwrite
    #pragma unroll
    for (int cc = 0; cc < 4; cc++) {
        float bc = cc == 0 ? b1v.x : cc == 1 ? b1v.y : cc == 2 ? b1v.z : b1v.w;
        #pragma unroll
        for (int rr = 0; rr < 4; rr++)
            Hs[(tx << 2) + cc][(ty << 2) + rr] = fmaxf(acc[rr][cc] + bc, 0.f);  // H2, k-major
    }
    __syncthreads();

    // GEMM2: H2 @ M2 (40 cols: tx<10 active)
    int bx = (tx < 10) ? (tx << 2) : 0;
    float acc2[4][4] = {};
    #pragma unroll 4
    for (int k = 0; k < 64; k++) {
        float4 a = *(const float4*)&Hs[k][ty << 2];
        float4 b = *(const float4*)&W2s[k][bx];
        FMA16(acc2, a, b)
    }
    float4 b2v = *(const float4*)(mb2 + bx);

    // softmax across 40 cols (10 tx-threads x 4) per row
    #pragma unroll
    for (int rr = 0; rr < 4; rr++) {
        float v0 = acc2[rr][0] + b2v.x, v1 = acc2[rr][1] + b2v.y;
        float v2 = acc2[rr][2] + b2v.z, v3 = acc2[rr][3] + b2v.w;
        float m = fmaxf(fmaxf(v0, v1), fmaxf(v2, v3));
        if (tx >= 10) m = -1e30f;
        #pragma unroll
        for (int s = 1; s < 16; s <<= 1) m = fmaxf(m, __shfl_xor(m, s));
        float e0 = __expf(v0 - m), e1 = __expf(v1 - m);
        float e2 = __expf(v2 - m), e3 = __expf(v3 - m);
        float sum = (tx < 10) ? (e0 + e1) + (e2 + e3) : 0.f;
        #pragma unroll
        for (int s = 1; s < 16; s <<= 1) sum += __shfl_xor(sum, s);
        float inv = 1.f / sum;
        int row = (ty << 2) + rr;
        if (tx < 10 && row < rows)
            *(float4*)(out + (size_t)(base + row) * OUTC + bx) =
                make_float4(e0 * inv, e1 * inv, e2 * inv, e3 * inv);
    }
}

extern "C" void kernel_launch(void* const* d_in, const int* in_sizes, int n_in,
                              void* d_out, int out_size, void* d_ws, size_t ws_size,
                              hipStream_t stream) {
    const float* x   = (const float*)d_in[0];
    const int*   ei  = (const int*)  d_in[1];
    const float* W1  = (const float*)d_in[2];
    const float* b1  = (const float*)d_in[3];
    const float* W2  = (const float*)d_in[4];
    const float* b2  = (const float*)d_in[5];
    const float* W3  = (const float*)d_in[6];
    const float* b3  = (const float*)d_in[7];
    const float* g1  = (const float*)d_in[8];
    const float* be1 = (const float*)d_in[9];
    const float* g2  = (const float*)d_in[10];
    const float* be2 = (const float*)d_in[11];
    const float* M1  = (const float*)d_in[12];
    const float* mb1 = (const float*)d_in[13];
    const float* M2  = (const float*)d_in[14];
    const float* mb2 = (const float*)d_in[15];

    const int IN_C = 128;
    int N = in_sizes[0] / IN_C;
    int E = in_sizes[1] / 2;
    const int* src = ei;
    const int* dst = ei + E;

    // workspace carve-up
    char* ws = (char*)d_ws;
    size_t off = 0;
    auto carve = [&](size_t bytes) -> void* {
        void* p = ws + off;
        off = (off + bytes + 255) & ~(size_t)255;
        return p;
    };
    int*   cnt  = (int*)  carve((size_t)N * sizeof(int));
    float* dinv = (float*)carve((size_t)N * sizeof(float));
    int*   recs = (int*)  carve((size_t)N * CAP * sizeof(int));
    float* HW   = (float*)carve((size_t)N * HID * sizeof(float));
    float* H    = (float*)carve((size_t)N * HID * sizeof(float));

    hipMemsetAsync(cnt, 0, (size_t)N * sizeof(int), stream);

    int eb = (E + 255) / 256;
    int nb = (N + 255) / 256;
    int rb = (N + 3) / 4;    // conv: one wave per node, 4 waves/block
    int tb = (N + 63) / 64;  // xform/convmlp: 64-row tile per 256-thread block

    fill_kernel<<<eb, 256, 0, stream>>>(src, dst, cnt, recs, E);
    dinv_kernel<<<nb, 256, 0, stream>>>(cnt, dinv, N);

    // layer 1
    xform_kernel<128><<<tb, 256, 0, stream>>>(x, W1, HW, N);
    conv_kernel<true><<<rb, 256, 0, stream>>>(HW, recs, cnt, dinv, b1, g1, be1, H, N);
    // layer 2
    xform_kernel<64><<<tb, 256, 0, stream>>>(H, W2, HW, N);
    conv_kernel<true><<<rb, 256, 0, stream>>>(HW, recs, cnt, dinv, b2, g2, be2, H, N);
    // layer 3 + MLP + softmax fused
    xform_kernel<64><<<tb, 256, 0, stream>>>(H, W3, HW, N);
    convmlp_kernel<<<tb, 256, 0, stream>>>(HW, recs, cnt, dinv, b3, M1, mb1, M2, mb2,
                                           (float*)d_out, N);
}

// Round 8
// 219.337 us; speedup vs baseline: 3.6359x; 1.1309x over previous
//
#include <hip/hip_runtime.h>
#include <math.h>

#define HID   64
#define OUTC  40
#define CAP   64   // max in-degree bucket capacity (Poisson(16): P(overflow) ~ 1e-13)

// ---------------- fused degree-count + bucket fill (single edge pass) ----------------
__global__ void fill_kernel(const int* __restrict__ src, const int* __restrict__ dst,
                            int* __restrict__ cnt, int* __restrict__ recs, int E) {
    int e = blockIdx.x * blockDim.x + threadIdx.x;
    if (e < E) {
        int d = dst[e];
        int pos = atomicAdd(&cnt[d], 1);
        if (pos < CAP) recs[(size_t)d * CAP + pos] = src[e];
    }
}

// dinv = rsqrt(deg+1)
__global__ void dinv_kernel(const int* __restrict__ cnt, float* __restrict__ dinv, int N) {
    int i = blockIdx.x * blockDim.x + threadIdx.x;
    if (i < N) dinv[i] = rsqrtf((float)cnt[i] + 1.0f);
}

#define FMA16(acc, a, b) \
    acc[0][0] = fmaf(a.x, b.x, acc[0][0]); acc[0][1] = fmaf(a.x, b.y, acc[0][1]); \
    acc[0][2] = fmaf(a.x, b.z, acc[0][2]); acc[0][3] = fmaf(a.x, b.w, acc[0][3]); \
    acc[1][0] = fmaf(a.y, b.x, acc[1][0]); acc[1][1] = fmaf(a.y, b.y, acc[1][1]); \
    acc[1][2] = fmaf(a.y, b.z, acc[1][2]); acc[1][3] = fmaf(a.y, b.w, acc[1][3]); \
    acc[2][0] = fmaf(a.z, b.x, acc[2][0]); acc[2][1] = fmaf(a.z, b.y, acc[2][1]); \
    acc[2][2] = fmaf(a.z, b.z, acc[2][2]); acc[2][3] = fmaf(a.z, b.w, acc[2][3]); \
    acc[3][0] = fmaf(a.w, b.x, acc[3][0]); acc[3][1] = fmaf(a.w, b.y, acc[3][1]); \
    acc[3][2] = fmaf(a.w, b.z, acc[3][2]); acc[3][3] = fmaf(a.w, b.w, acc[3][3]);

// ---------------- dense transform: out[N,64] = X[N,CIN] @ W[CIN,64] ----------------
template<int CIN>
__global__ __launch_bounds__(256) void xform_kernel(const float* __restrict__ X,
                                                    const float* __restrict__ W,
                                                    float* __restrict__ out, int N) {
    __shared__ float Xs[CIN][68];   // k-major
    __shared__ float Ws[CIN][68];
    int tid = threadIdx.x;
    int base = blockIdx.x << 6;
    int rows = N - base; if (rows > 64) rows = 64;

    {   // stage W
        int k = tid >> 4, c = (tid & 15) << 2;
        #pragma unroll
        for (int k0 = 0; k0 < CIN; k0 += 16) {
            float4 wv = *(const float4*)(W + (size_t)((k0 + k) << 6) + c);
            *(float4*)&Ws[k0 + k][c] = wv;
        }
    }
    {   // stage X transposed to k-major
        int r = tid >> 2, q = (tid & 3) << 2;
        int rc = r < rows ? r : 0;
        const float* xp = X + (size_t)(base + rc) * CIN + q;
        #pragma unroll
        for (int k0 = 0; k0 < CIN; k0 += 16) {
            float4 xv = *(const float4*)(xp + k0);
            Xs[k0 + q + 0][r] = xv.x;
            Xs[k0 + q + 1][r] = xv.y;
            Xs[k0 + q + 2][r] = xv.z;
            Xs[k0 + q + 3][r] = xv.w;
        }
    }
    __syncthreads();

    int tx = tid & 15, ty = tid >> 4;
    float acc[4][4] = {};
    #pragma unroll 4
    for (int k = 0; k < CIN; k++) {
        float4 a = *(const float4*)&Xs[k][ty << 2];
        float4 b = *(const float4*)&Ws[k][tx << 2];
        FMA16(acc, a, b)
    }
    #pragma unroll
    for (int rr = 0; rr < 4; rr++) {
        int row = (ty << 2) + rr;
        if (row < rows)
            *(float4*)(out + ((size_t)(base + row) << 6) + (tx << 2)) =
                make_float4(acc[rr][0], acc[rr][1], acc[rr][2], acc[rr][3]);
    }
}

// ---------------- gather-aggregate + self-loop + bias (+ LN + ReLU) ----------------
// float4 gather: 16 lanes x float4 cover one 256B row; 4 edges per VMEM instr.
// Group g = lane>>4 handles edges k+g+{0,4,8,12}; cross-group shfl_xor reduce.
template<bool LN>
__global__ void conv_kernel(const float* __restrict__ hw, const int* __restrict__ recs,
                            const int* __restrict__ cnt, const float* __restrict__ dinv,
                            const float* __restrict__ b, const float* __restrict__ g,
                            const float* __restrict__ be, float* __restrict__ out, int N) {
    int lane = threadIdx.x & 63;
    int row  = (blockIdx.x << 2) + (threadIdx.x >> 6);
    if (row >= N) return;

    int c = cnt[row];
    if (c > CAP) c = CAP;

    int s_l = 0; float ds_l = 0.f;     // masked slots contribute 0
    if (lane < c) { s_l = recs[(size_t)row * CAP + lane]; ds_l = dinv[s_l]; }

    int g4 = lane >> 4, j = lane & 15;
    const float4* hw4 = (const float4*)hw;
    float di = dinv[row];
    float4 self4 = hw4[(size_t)row * 16 + j];     // issue early

    float4 a0 = {0,0,0,0}, a1 = {0,0,0,0}, a2 = {0,0,0,0}, a3 = {0,0,0,0};
    int kmax = (c + 15) & ~15;
    for (int k = 0; k < kmax; k += 16) {
        int   s0 = __shfl(s_l, k + g4 + 0), s1 = __shfl(s_l, k + g4 + 4);
        int   s2 = __shfl(s_l, k + g4 + 8), s3 = __shfl(s_l, k + g4 + 12);
        float e0 = __shfl(ds_l, k + g4 + 0), e1 = __shfl(ds_l, k + g4 + 4);
        float e2 = __shfl(ds_l, k + g4 + 8), e3 = __shfl(ds_l, k + g4 + 12);
        float4 v0 = hw4[(size_t)s0 * 16 + j];
        float4 v1 = hw4[(size_t)s1 * 16 + j];
        float4 v2 = hw4[(size_t)s2 * 16 + j];
        float4 v3 = hw4[(size_t)s3 * 16 + j];
        a0.x = fmaf(e0, v0.x, a0.x); a0.y = fmaf(e0, v0.y, a0.y);
        a0.z = fmaf(e0, v0.z, a0.z); a0.w = fmaf(e0, v0.w, a0.w);
        a1.x = fmaf(e1, v1.x, a1.x); a1.y = fmaf(e1, v1.y, a1.y);
        a1.z = fmaf(e1, v1.z, a1.z); a1.w = fmaf(e1, v1.w, a1.w);
        a2.x = fmaf(e2, v2.x, a2.x); a2.y = fmaf(e2, v2.y, a2.y);
        a2.z = fmaf(e2, v2.z, a2.z); a2.w = fmaf(e2, v2.w, a2.w);
        a3.x = fmaf(e3, v3.x, a3.x); a3.y = fmaf(e3, v3.y, a3.y);
        a3.z = fmaf(e3, v3.z, a3.z); a3.w = fmaf(e3, v3.w, a3.w);
    }
    float4 acc;
    acc.x = (a0.x + a1.x) + (a2.x + a3.x);
    acc.y = (a0.y + a1.y) + (a2.y + a3.y);
    acc.z = (a0.z + a1.z) + (a2.z + a3.z);
    acc.w = (a0.w + a1.w) + (a2.w + a3.w);
    // cross-group reduce (groups differ, feature layout identical)
    acc.x += __shfl_xor(acc.x, 16); acc.y += __shfl_xor(acc.y, 16);
    acc.z += __shfl_xor(acc.z, 16); acc.w += __shfl_xor(acc.w, 16);
    acc.x += __shfl_xor(acc.x, 32); acc.y += __shfl_xor(acc.y, 32);
    acc.z += __shfl_xor(acc.z, 32); acc.w += __shfl_xor(acc.w, 32);

    float4 b4 = ((const float4*)b)[j];
    float dd = di * di;
    acc.x = fmaf(di, acc.x, fmaf(dd, self4.x, b4.x));
    acc.y = fmaf(di, acc.y, fmaf(dd, self4.y, b4.y));
    acc.z = fmaf(di, acc.z, fmaf(dd, self4.z, b4.z));
    acc.w = fmaf(di, acc.w, fmaf(dd, self4.w, b4.w));

    if (LN) {
        float s = (acc.x + acc.y) + (acc.z + acc.w);
        #pragma unroll
        for (int o = 8; o; o >>= 1) s += __shfl_xor(s, o);
        float mu = s * (1.f / 64.f);
        float4 d0 = make_float4(acc.x - mu, acc.y - mu, acc.z - mu, acc.w - mu);
        float v = (d0.x * d0.x + d0.y * d0.y) + (d0.z * d0.z + d0.w * d0.w);
        #pragma unroll
        for (int o = 8; o; o >>= 1) v += __shfl_xor(v, o);
        float r = rsqrtf(v * (1.f / 64.f) + 1e-5f);
        float4 g4v = ((const float4*)g)[j];
        float4 be4 = ((const float4*)be)[j];
        acc.x = fmaxf(fmaf(d0.x * r, g4v.x, be4.x), 0.f);
        acc.y = fmaxf(fmaf(d0.y * r, g4v.y, be4.y), 0.f);
        acc.z = fmaxf(fmaf(d0.z * r, g4v.z, be4.z), 0.f);
        acc.w = fmaxf(fmaf(d0.w * r, g4v.w, be4.w), 0.f);
    }
    if (g4 == 0) ((float4*)out)[(size_t)row * 16 + j] = acc;
}

// ---------------- MLP (64->64 relu ->40) + softmax (round-6 proven) ----------------
__global__ __launch_bounds__(256) void mlp_kernel(const float* __restrict__ h,
                           const float* __restrict__ M1, const float* __restrict__ mb1,
                           const float* __restrict__ M2, const float* __restrict__ mb2,
                           float* __restrict__ out, int N) {
    __shared__ float Hs [64][68];
    __shared__ float W1s[64][68];
    __shared__ float H2s[64][68];
    __shared__ float W2s[64][44];
    int tid = threadIdx.x;
    int base = blockIdx.x << 6;
    int rows = N - base; if (rows > 64) rows = 64;

    {   // stage M1
        int k = tid >> 4, c = (tid & 15) << 2;
        #pragma unroll
        for (int k0 = 0; k0 < 64; k0 += 16) {
            float4 wv = *(const float4*)(M1 + (size_t)((k0 + k) << 6) + c);
            *(float4*)&W1s[k0 + k][c] = wv;
        }
    }
    for (int i = tid; i < 64 * OUTC; i += 256)
        W2s[i / OUTC][i % OUTC] = M2[i];
    {   // stage h transposed
        int r = tid >> 2, q = (tid & 3) << 2;
        int rc = r < rows ? r : 0;
        const float* xp = h + (((size_t)(base + rc)) << 6) + q;
        #pragma unroll
        for (int k0 = 0; k0 < 64; k0 += 16) {
            float4 xv = *(const float4*)(xp + k0);
            Hs[k0 + q + 0][r] = xv.x;
            Hs[k0 + q + 1][r] = xv.y;
            Hs[k0 + q + 2][r] = xv.z;
            Hs[k0 + q + 3][r] = xv.w;
        }
    }
    __syncthreads();

    int tx = tid & 15, ty = tid >> 4;

    float acc[4][4] = {};
    #pragma unroll 4
    for (int k = 0; k < 64; k++) {
        float4 a = *(const float4*)&Hs[k][ty << 2];
        float4 b = *(const float4*)&W1s[k][tx << 2];
        FMA16(acc, a, b)
    }
    float4 b1v = *(const float4*)(mb1 + (tx << 2));
    #pragma unroll
    for (int cc = 0; cc < 4; cc++) {
        float bc = cc == 0 ? b1v.x : cc == 1 ? b1v.y : cc == 2 ? b1v.z : b1v.w;
        #pragma unroll
        for (int rr = 0; rr < 4; rr++)
            H2s[(tx << 2) + cc][(ty << 2) + rr] = fmaxf(acc[rr][cc] + bc, 0.f);
    }
    __syncthreads();

    int bx = (tx < 10) ? (tx << 2) : 0;
    float acc2[4][4] = {};
    #pragma unroll 4
    for (int k = 0; k < 64; k++) {
        float4 a = *(const float4*)&H2s[k][ty << 2];
        float4 b = *(const float4*)&W2s[k][bx];
        FMA16(acc2, a, b)
    }
    float4 b2v = *(const float4*)(mb2 + bx);

    #pragma unroll
    for (int rr = 0; rr < 4; rr++) {
        float v0 = acc2[rr][0] + b2v.x, v1 = acc2[rr][1] + b2v.y;
        float v2 = acc2[rr][2] + b2v.z, v3 = acc2[rr][3] + b2v.w;
        float m = fmaxf(fmaxf(v0, v1), fmaxf(v2, v3));
        if (tx >= 10) m = -1e30f;
        #pragma unroll
        for (int s = 1; s < 16; s <<= 1) m = fmaxf(m, __shfl_xor(m, s));
        float e0 = __expf(v0 - m), e1 = __expf(v1 - m);
        float e2 = __expf(v2 - m), e3 = __expf(v3 - m);
        float sum = (tx < 10) ? (e0 + e1) + (e2 + e3) : 0.f;
        #pragma unroll
        for (int s = 1; s < 16; s <<= 1) sum += __shfl_xor(sum, s);
        float inv = 1.f / sum;
        int row = (ty << 2) + rr;
        if (tx < 10 && row < rows)
            *(float4*)(out + (size_t)(base + row) * OUTC + bx) =
                make_float4(e0 * inv, e1 * inv, e2 * inv, e3 * inv);
    }
}

extern "C" void kernel_launch(void* const* d_in, const int* in_sizes, int n_in,
                              void* d_out, int out_size, void* d_ws, size_t ws_size,
                              hipStream_t stream) {
    const float* x   = (const float*)d_in[0];
    const int*   ei  = (const int*)  d_in[1];
    const float* W1  = (const float*)d_in[2];
    const float* b1  = (const float*)d_in[3];
    const float* W2  = (const float*)d_in[4];
    const float* b2  = (const float*)d_in[5];
    const float* W3  = (const float*)d_in[6];
    const float* b3  = (const float*)d_in[7];
    const float* g1  = (const float*)d_in[8];
    const float* be1 = (const float*)d_in[9];
    const float* g2  = (const float*)d_in[10];
    const float* be2 = (const float*)d_in[11];
    const float* M1  = (const float*)d_in[12];
    const float* mb1 = (const float*)d_in[13];
    const float* M2  = (const float*)d_in[14];
    const float* mb2 = (const float*)d_in[15];

    const int IN_C = 128;
    int N = in_sizes[0] / IN_C;
    int E = in_sizes[1] / 2;
    const int* src = ei;
    const int* dst = ei + E;

    char* ws = (char*)d_ws;
    size_t off = 0;
    auto carve = [&](size_t bytes) -> void* {
        void* p = ws + off;
        off = (off + bytes + 255) & ~(size_t)255;
        return p;
    };
    int*   cnt  = (int*)  carve((size_t)N * sizeof(int));
    float* dinv = (float*)carve((size_t)N * sizeof(float));
    int*   recs = (int*)  carve((size_t)N * CAP * sizeof(int));
    float* HW   = (float*)carve((size_t)N * HID * sizeof(float));
    float* H    = (float*)carve((size_t)N * HID * sizeof(float));

    hipMemsetAsync(cnt, 0, (size_t)N * sizeof(int), stream);

    int eb = (E + 255) / 256;
    int nb = (N + 255) / 256;
    int rb = (N + 3) / 4;    // conv: one wave per node, 4 waves/block
    int tb = (N + 63) / 64;  // xform/mlp: 64-row tile per 256-thread block

    fill_kernel<<<eb, 256, 0, stream>>>(src, dst, cnt, recs, E);
    dinv_kernel<<<nb, 256, 0, stream>>>(cnt, dinv, N);

    // layer 1
    xform_kernel<128><<<tb, 256, 0, stream>>>(x, W1, HW, N);
    conv_kernel<true><<<rb, 256, 0, stream>>>(HW, recs, cnt, dinv, b1, g1, be1, H, N);
    // layer 2
    xform_kernel<64><<<tb, 256, 0, stream>>>(H, W2, HW, N);
    conv_kernel<true><<<rb, 256, 0, stream>>>(HW, recs, cnt, dinv, b2, g2, be2, H, N);
    // layer 3 (no LN/ReLU)
    xform_kernel<64><<<tb, 256, 0, stream>>>(H, W3, HW, N);
    conv_kernel<false><<<rb, 256, 0, stream>>>(HW, recs, cnt, dinv, b3, nullptr, nullptr, H, N);

    // MLP + softmax
    mlp_kernel<<<tb, 256, 0, stream>>>(H, M1, mb1, M2, mb2, (float*)d_out, N);
}

// Round 9
// 209.613 us; speedup vs baseline: 3.8045x; 1.0464x over previous
//
#include <hip/hip_runtime.h>
#include <math.h>

#define HID   64
#define OUTC  40
#define CAP   64   // max in-degree bucket capacity (Poisson(16): P(overflow) ~ 1e-13)

// ---------------- XCD-sliced degree-count + bucket fill ----------------
// Group g = blockIdx&7 (maps to XCD g under the observed bid%8 round-robin)
// scans ALL edges, commits only dst-slice g. Each recs line is then written
// by exactly one XCD -> single L2 writeback instead of ~4 partial ones.
__global__ void fill_kernel(const int* __restrict__ src, const int* __restrict__ dst,
                            int* __restrict__ cnt, int* __restrict__ recs,
                            int E, int N) {
    int g    = blockIdx.x & 7;
    int gblk = blockIdx.x >> 3;
    int nblk = gridDim.x >> 3;
    int slice = (N + 7) >> 3;
    int lo = g * slice;
    int hi = lo + slice; if (hi > N) hi = N;
    for (int e = gblk * blockDim.x + threadIdx.x; e < E; e += nblk * blockDim.x) {
        int d = dst[e];
        if (d >= lo && d < hi) {
            int pos = atomicAdd(&cnt[d], 1);
            if (pos < CAP) recs[(size_t)d * CAP + pos] = src[e];
        }
    }
}

// dinv = rsqrt(deg+1)
__global__ void dinv_kernel(const int* __restrict__ cnt, float* __restrict__ dinv, int N) {
    int i = blockIdx.x * blockDim.x + threadIdx.x;
    if (i < N) dinv[i] = rsqrtf((float)cnt[i] + 1.0f);
}

#define FMA16(acc, a, b) \
    acc[0][0] = fmaf(a.x, b.x, acc[0][0]); acc[0][1] = fmaf(a.x, b.y, acc[0][1]); \
    acc[0][2] = fmaf(a.x, b.z, acc[0][2]); acc[0][3] = fmaf(a.x, b.w, acc[0][3]); \
    acc[1][0] = fmaf(a.y, b.x, acc[1][0]); acc[1][1] = fmaf(a.y, b.y, acc[1][1]); \
    acc[1][2] = fmaf(a.y, b.z, acc[1][2]); acc[1][3] = fmaf(a.y, b.w, acc[1][3]); \
    acc[2][0] = fmaf(a.z, b.x, acc[2][0]); acc[2][1] = fmaf(a.z, b.y, acc[2][1]); \
    acc[2][2] = fmaf(a.z, b.z, acc[2][2]); acc[2][3] = fmaf(a.z, b.w, acc[2][3]); \
    acc[3][0] = fmaf(a.w, b.x, acc[3][0]); acc[3][1] = fmaf(a.w, b.y, acc[3][1]); \
    acc[3][2] = fmaf(a.w, b.z, acc[3][2]); acc[3][3] = fmaf(a.w, b.w, acc[3][3]);

// ---------------- dense transform: out[N,64] = X[N,CIN] @ W[CIN,64] ----------------
template<int CIN>
__global__ __launch_bounds__(256) void xform_kernel(const float* __restrict__ X,
                                                    const float* __restrict__ W,
                                                    float* __restrict__ out, int N) {
    __shared__ float Xs[CIN][68];   // k-major
    __shared__ float Ws[CIN][68];
    int tid = threadIdx.x;
    int base = blockIdx.x << 6;
    int rows = N - base; if (rows > 64) rows = 64;

    {   // stage W
        int k = tid >> 4, c = (tid & 15) << 2;
        #pragma unroll
        for (int k0 = 0; k0 < CIN; k0 += 16) {
            float4 wv = *(const float4*)(W + (size_t)((k0 + k) << 6) + c);
            *(float4*)&Ws[k0 + k][c] = wv;
        }
    }
    {   // stage X transposed to k-major
        int r = tid >> 2, q = (tid & 3) << 2;
        int rc = r < rows ? r : 0;
        const float* xp = X + (size_t)(base + rc) * CIN + q;
        #pragma unroll
        for (int k0 = 0; k0 < CIN; k0 += 16) {
            float4 xv = *(const float4*)(xp + k0);
            Xs[k0 + q + 0][r] = xv.x;
            Xs[k0 + q + 1][r] = xv.y;
            Xs[k0 + q + 2][r] = xv.z;
            Xs[k0 + q + 3][r] = xv.w;
        }
    }
    __syncthreads();

    int tx = tid & 15, ty = tid >> 4;
    float acc[4][4] = {};
    #pragma unroll 4
    for (int k = 0; k < CIN; k++) {
        float4 a = *(const float4*)&Xs[k][ty << 2];
        float4 b = *(const float4*)&Ws[k][tx << 2];
        FMA16(acc, a, b)
    }
    #pragma unroll
    for (int rr = 0; rr < 4; rr++) {
        int row = (ty << 2) + rr;
        if (row < rows)
            *(float4*)(out + ((size_t)(base + row) << 6) + (tx << 2)) =
                make_float4(acc[rr][0], acc[rr][1], acc[rr][2], acc[rr][3]);
    }
}

// ---------------- gather-aggregate + self-loop + bias (+ LN + ReLU) ----------------
// float4 gather: 16 lanes x float4 cover one 256B row; 4 edges per VMEM instr.
template<bool LN>
__global__ void conv_kernel(const float* __restrict__ hw, const int* __restrict__ recs,
                            const int* __restrict__ cnt, const float* __restrict__ dinv,
                            const float* __restrict__ b, const float* __restrict__ g,
                            const float* __restrict__ be, float* __restrict__ out, int N) {
    int lane = threadIdx.x & 63;
    int row  = (blockIdx.x << 2) + (threadIdx.x >> 6);
    if (row >= N) return;

    int c = cnt[row];
    if (c > CAP) c = CAP;

    int s_l = 0; float ds_l = 0.f;     // masked slots contribute 0
    if (lane < c) { s_l = recs[(size_t)row * CAP + lane]; ds_l = dinv[s_l]; }

    int g4 = lane >> 4, j = lane & 15;
    const float4* hw4 = (const float4*)hw;
    float di = dinv[row];
    float4 self4 = hw4[(size_t)row * 16 + j];     // issue early

    float4 a0 = {0,0,0,0}, a1 = {0,0,0,0}, a2 = {0,0,0,0}, a3 = {0,0,0,0};
    int kmax = (c + 15) & ~15;
    for (int k = 0; k < kmax; k += 16) {
        int   s0 = __shfl(s_l, k + g4 + 0), s1 = __shfl(s_l, k + g4 + 4);
        int   s2 = __shfl(s_l, k + g4 + 8), s3 = __shfl(s_l, k + g4 + 12);
        float e0 = __shfl(ds_l, k + g4 + 0), e1 = __shfl(ds_l, k + g4 + 4);
        float e2 = __shfl(ds_l, k + g4 + 8), e3 = __shfl(ds_l, k + g4 + 12);
        float4 v0 = hw4[(size_t)s0 * 16 + j];
        float4 v1 = hw4[(size_t)s1 * 16 + j];
        float4 v2 = hw4[(size_t)s2 * 16 + j];
        float4 v3 = hw4[(size_t)s3 * 16 + j];
        a0.x = fmaf(e0, v0.x, a0.x); a0.y = fmaf(e0, v0.y, a0.y);
        a0.z = fmaf(e0, v0.z, a0.z); a0.w = fmaf(e0, v0.w, a0.w);
        a1.x = fmaf(e1, v1.x, a1.x); a1.y = fmaf(e1, v1.y, a1.y);
        a1.z = fmaf(e1, v1.z, a1.z); a1.w = fmaf(e1, v1.w, a1.w);
        a2.x = fmaf(e2, v2.x, a2.x); a2.y = fmaf(e2, v2.y, a2.y);
        a2.z = fmaf(e2, v2.z, a2.z); a2.w = fmaf(e2, v2.w, a2.w);
        a3.x = fmaf(e3, v3.x, a3.x); a3.y = fmaf(e3, v3.y, a3.y);
        a3.z = fmaf(e3, v3.z, a3.z); a3.w = fmaf(e3, v3.w, a3.w);
    }
    float4 acc;
    acc.x = (a0.x + a1.x) + (a2.x + a3.x);
    acc.y = (a0.y + a1.y) + (a2.y + a3.y);
    acc.z = (a0.z + a1.z) + (a2.z + a3.z);
    acc.w = (a0.w + a1.w) + (a2.w + a3.w);
    acc.x += __shfl_xor(acc.x, 16); acc.y += __shfl_xor(acc.y, 16);
    acc.z += __shfl_xor(acc.z, 16); acc.w += __shfl_xor(acc.w, 16);
    acc.x += __shfl_xor(acc.x, 32); acc.y += __shfl_xor(acc.y, 32);
    acc.z += __shfl_xor(acc.z, 32); acc.w += __shfl_xor(acc.w, 32);

    float4 b4 = ((const float4*)b)[j];
    float dd = di * di;
    acc.x = fmaf(di, acc.x, fmaf(dd, self4.x, b4.x));
    acc.y = fmaf(di, acc.y, fmaf(dd, self4.y, b4.y));
    acc.z = fmaf(di, acc.z, fmaf(dd, self4.z, b4.z));
    acc.w = fmaf(di, acc.w, fmaf(dd, self4.w, b4.w));

    if (LN) {
        float s = (acc.x + acc.y) + (acc.z + acc.w);
        #pragma unroll
        for (int o = 8; o; o >>= 1) s += __shfl_xor(s, o);
        float mu = s * (1.f / 64.f);
        float4 d0 = make_float4(acc.x - mu, acc.y - mu, acc.z - mu, acc.w - mu);
        float v = (d0.x * d0.x + d0.y * d0.y) + (d0.z * d0.z + d0.w * d0.w);
        #pragma unroll
        for (int o = 8; o; o >>= 1) v += __shfl_xor(v, o);
        float r = rsqrtf(v * (1.f / 64.f) + 1e-5f);
        float4 g4v = ((const float4*)g)[j];
        float4 be4 = ((const float4*)be)[j];
        acc.x = fmaxf(fmaf(d0.x * r, g4v.x, be4.x), 0.f);
        acc.y = fmaxf(fmaf(d0.y * r, g4v.y, be4.y), 0.f);
        acc.z = fmaxf(fmaf(d0.z * r, g4v.z, be4.z), 0.f);
        acc.w = fmaxf(fmaf(d0.w * r, g4v.w, be4.w), 0.f);
    }
    if (g4 == 0) ((float4*)out)[(size_t)row * 16 + j] = acc;
}

// ---------------- MLP (64->64 relu ->40) + softmax ----------------
__global__ __launch_bounds__(256) void mlp_kernel(const float* __restrict__ h,
                           const float* __restrict__ M1, const float* __restrict__ mb1,
                           const float* __restrict__ M2, const float* __restrict__ mb2,
                           float* __restrict__ out, int N) {
    __shared__ float Hs [64][68];
    __shared__ float W1s[64][68];
    __shared__ float H2s[64][68];
    __shared__ float W2s[64][44];
    int tid = threadIdx.x;
    int base = blockIdx.x << 6;
    int rows = N - base; if (rows > 64) rows = 64;

    {   // stage M1
        int k = tid >> 4, c = (tid & 15) << 2;
        #pragma unroll
        for (int k0 = 0; k0 < 64; k0 += 16) {
            float4 wv = *(const float4*)(M1 + (size_t)((k0 + k) << 6) + c);
            *(float4*)&W1s[k0 + k][c] = wv;
        }
    }
    for (int i = tid; i < 64 * OUTC; i += 256)
        W2s[i / OUTC][i % OUTC] = M2[i];
    {   // stage h transposed
        int r = tid >> 2, q = (tid & 3) << 2;
        int rc = r < rows ? r : 0;
        const float* xp = h + (((size_t)(base + rc)) << 6) + q;
        #pragma unroll
        for (int k0 = 0; k0 < 64; k0 += 16) {
            float4 xv = *(const float4*)(xp + k0);
            Hs[k0 + q + 0][r] = xv.x;
            Hs[k0 + q + 1][r] = xv.y;
            Hs[k0 + q + 2][r] = xv.z;
            Hs[k0 + q + 3][r] = xv.w;
        }
    }
    __syncthreads();

    int tx = tid & 15, ty = tid >> 4;

    float acc[4][4] = {};
    #pragma unroll 4
    for (int k = 0; k < 64; k++) {
        float4 a = *(const float4*)&Hs[k][ty << 2];
        float4 b = *(const float4*)&W1s[k][tx << 2];
        FMA16(acc, a, b)
    }
    float4 b1v = *(const float4*)(mb1 + (tx << 2));
    #pragma unroll
    for (int cc = 0; cc < 4; cc++) {
        float bc = cc == 0 ? b1v.x : cc == 1 ? b1v.y : cc == 2 ? b1v.z : b1v.w;
        #pragma unroll
        for (int rr = 0; rr < 4; rr++)
            H2s[(tx << 2) + cc][(ty << 2) + rr] = fmaxf(acc[rr][cc] + bc, 0.f);
    }
    __syncthreads();

    int bx = (tx < 10) ? (tx << 2) : 0;
    float acc2[4][4] = {};
    #pragma unroll 4
    for (int k = 0; k < 64; k++) {
        float4 a = *(const float4*)&H2s[k][ty << 2];
        float4 b = *(const float4*)&W2s[k][bx];
        FMA16(acc2, a, b)
    }
    float4 b2v = *(const float4*)(mb2 + bx);

    #pragma unroll
    for (int rr = 0; rr < 4; rr++) {
        float v0 = acc2[rr][0] + b2v.x, v1 = acc2[rr][1] + b2v.y;
        float v2 = acc2[rr][2] + b2v.z, v3 = acc2[rr][3] + b2v.w;
        float m = fmaxf(fmaxf(v0, v1), fmaxf(v2, v3));
        if (tx >= 10) m = -1e30f;
        #pragma unroll
        for (int s = 1; s < 16; s <<= 1) m = fmaxf(m, __shfl_xor(m, s));
        float e0 = __expf(v0 - m), e1 = __expf(v1 - m);
        float e2 = __expf(v2 - m), e3 = __expf(v3 - m);
        float sum = (tx < 10) ? (e0 + e1) + (e2 + e3) : 0.f;
        #pragma unroll
        for (int s = 1; s < 16; s <<= 1) sum += __shfl_xor(sum, s);
        float inv = 1.f / sum;
        int row = (ty << 2) + rr;
        if (tx < 10 && row < rows)
            *(float4*)(out + (size_t)(base + row) * OUTC + bx) =
                make_float4(e0 * inv, e1 * inv, e2 * inv, e3 * inv);
    }
}

extern "C" void kernel_launch(void* const* d_in, const int* in_sizes, int n_in,
                              void* d_out, int out_size, void* d_ws, size_t ws_size,
                              hipStream_t stream) {
    const float* x   = (const float*)d_in[0];
    const int*   ei  = (const int*)  d_in[1];
    const float* W1  = (const float*)d_in[2];
    const float* b1  = (const float*)d_in[3];
    const float* W2  = (const float*)d_in[4];
    const float* b2  = (const float*)d_in[5];
    const float* W3  = (const float*)d_in[6];
    const float* b3  = (const float*)d_in[7];
    const float* g1  = (const float*)d_in[8];
    const float* be1 = (const float*)d_in[9];
    const float* g2  = (const float*)d_in[10];
    const float* be2 = (const float*)d_in[11];
    const float* M1  = (const float*)d_in[12];
    const float* mb1 = (const float*)d_in[13];
    const float* M2  = (const float*)d_in[14];
    const float* mb2 = (const float*)d_in[15];

    const int IN_C = 128;
    int N = in_sizes[0] / IN_C;
    int E = in_sizes[1] / 2;
    const int* src = ei;
    const int* dst = ei + E;

    char* ws = (char*)d_ws;
    size_t off = 0;
    auto carve = [&](size_t bytes) -> void* {
        void* p = ws + off;
        off = (off + bytes + 255) & ~(size_t)255;
        return p;
    };
    int*   cnt  = (int*)  carve((size_t)N * sizeof(int));
    float* dinv = (float*)carve((size_t)N * sizeof(float));
    int*   recs = (int*)  carve((size_t)N * CAP * sizeof(int));
    float* HW   = (float*)carve((size_t)N * HID * sizeof(float));
    float* H    = (float*)carve((size_t)N * HID * sizeof(float));

    hipMemsetAsync(cnt, 0, (size_t)N * sizeof(int), stream);

    int nb = (N + 255) / 256;
    int rb = (N + 3) / 4;    // conv: one wave per node, 4 waves/block
    int tb = (N + 63) / 64;  // xform/mlp: 64-row tile per 256-thread block

    fill_kernel<<<2048, 256, 0, stream>>>(src, dst, cnt, recs, E, N);
    dinv_kernel<<<nb, 256, 0, stream>>>(cnt, dinv, N);

    // layer 1
    xform_kernel<128><<<tb, 256, 0, stream>>>(x, W1, HW, N);
    conv_kernel<true><<<rb, 256, 0, stream>>>(HW, recs, cnt, dinv, b1, g1, be1, H, N);
    // layer 2
    xform_kernel<64><<<tb, 256, 0, stream>>>(H, W2, HW, N);
    conv_kernel<true><<<rb, 256, 0, stream>>>(HW, recs, cnt, dinv, b2, g2, be2, H, N);
    // layer 3 (no LN/ReLU)
    xform_kernel<64><<<tb, 256, 0, stream>>>(H, W3, HW, N);
    conv_kernel<false><<<rb, 256, 0, stream>>>(HW, recs, cnt, dinv, b3, nullptr, nullptr, H, N);

    // MLP + softmax
    mlp_kernel<<<tb, 256, 0, stream>>>(H, M1, mb1, M2, mb2, (float*)d_out, N);
}

// Round 10
// 209.559 us; speedup vs baseline: 3.8055x; 1.0003x over previous
//
#include <hip/hip_runtime.h>
#include <math.h>

#define HID   64
#define OUTC  40
#define CAP   64   // max in-degree bucket capacity (Poisson(16): P(overflow) ~ 1e-13)

// ---------------- zero cnt (rocclr fillBuffer is ~43us for 200KB; this is ~2us) ----
__global__ void zero_kernel(int4* __restrict__ p, int n4) {
    int i = blockIdx.x * blockDim.x + threadIdx.x;
    if (i < n4) p[i] = make_int4(0, 0, 0, 0);
}

// ---------------- XCD-sliced degree-count + bucket fill ----------------
// Group g = blockIdx&7 scans ALL edges, commits only dst-slice g -> each recs
// line is written by exactly one XCD (single L2 writeback).
__global__ void fill_kernel(const int* __restrict__ src, const int* __restrict__ dst,
                            int* __restrict__ cnt, int* __restrict__ recs,
                            int E, int N) {
    int g    = blockIdx.x & 7;
    int gblk = blockIdx.x >> 3;
    int nblk = gridDim.x >> 3;
    int slice = (N + 7) >> 3;
    int lo = g * slice;
    int hi = lo + slice; if (hi > N) hi = N;
    for (int e = gblk * blockDim.x + threadIdx.x; e < E; e += nblk * blockDim.x) {
        int d = dst[e];
        if (d >= lo && d < hi) {
            int pos = atomicAdd(&cnt[d], 1);
            if (pos < CAP) recs[(size_t)d * CAP + pos] = src[e];
        }
    }
}

// dinv = rsqrt(deg+1)
__global__ void dinv_kernel(const int* __restrict__ cnt, float* __restrict__ dinv, int N) {
    int i = blockIdx.x * blockDim.x + threadIdx.x;
    if (i < N) dinv[i] = rsqrtf((float)cnt[i] + 1.0f);
}

#define FMA16(acc, a, b) \
    acc[0][0] = fmaf(a.x, b.x, acc[0][0]); acc[0][1] = fmaf(a.x, b.y, acc[0][1]); \
    acc[0][2] = fmaf(a.x, b.z, acc[0][2]); acc[0][3] = fmaf(a.x, b.w, acc[0][3]); \
    acc[1][0] = fmaf(a.y, b.x, acc[1][0]); acc[1][1] = fmaf(a.y, b.y, acc[1][1]); \
    acc[1][2] = fmaf(a.y, b.z, acc[1][2]); acc[1][3] = fmaf(a.y, b.w, acc[1][3]); \
    acc[2][0] = fmaf(a.z, b.x, acc[2][0]); acc[2][1] = fmaf(a.z, b.y, acc[2][1]); \
    acc[2][2] = fmaf(a.z, b.z, acc[2][2]); acc[2][3] = fmaf(a.z, b.w, acc[2][3]); \
    acc[3][0] = fmaf(a.w, b.x, acc[3][0]); acc[3][1] = fmaf(a.w, b.y, acc[3][1]); \
    acc[3][2] = fmaf(a.w, b.z, acc[3][2]); acc[3][3] = fmaf(a.w, b.w, acc[3][3]);

// ---------------- dense transform: out[N,64] = X[N,CIN] @ W[CIN,64] ----------------
template<int CIN>
__global__ __launch_bounds__(256) void xform_kernel(const float* __restrict__ X,
                                                    const float* __restrict__ W,
                                                    float* __restrict__ out, int N) {
    __shared__ float Xs[CIN][68];   // k-major
    __shared__ float Ws[CIN][68];
    int tid = threadIdx.x;
    int base = blockIdx.x << 6;
    int rows = N - base; if (rows > 64) rows = 64;

    {   // stage W
        int k = tid >> 4, c = (tid & 15) << 2;
        #pragma unroll
        for (int k0 = 0; k0 < CIN; k0 += 16) {
            float4 wv = *(const float4*)(W + (size_t)((k0 + k) << 6) + c);
            *(float4*)&Ws[k0 + k][c] = wv;
        }
    }
    {   // stage X transposed to k-major
        int r = tid >> 2, q = (tid & 3) << 2;
        int rc = r < rows ? r : 0;
        const float* xp = X + (size_t)(base + rc) * CIN + q;
        #pragma unroll
        for (int k0 = 0; k0 < CIN; k0 += 16) {
            float4 xv = *(const float4*)(xp + k0);
            Xs[k0 + q + 0][r] = xv.x;
            Xs[k0 + q + 1][r] = xv.y;
            Xs[k0 + q + 2][r] = xv.z;
            Xs[k0 + q + 3][r] = xv.w;
        }
    }
    __syncthreads();

    int tx = tid & 15, ty = tid >> 4;
    float acc[4][4] = {};
    #pragma unroll 4
    for (int k = 0; k < CIN; k++) {
        float4 a = *(const float4*)&Xs[k][ty << 2];
        float4 b = *(const float4*)&Ws[k][tx << 2];
        FMA16(acc, a, b)
    }
    #pragma unroll
    for (int rr = 0; rr < 4; rr++) {
        int row = (ty << 2) + rr;
        if (row < rows)
            *(float4*)(out + ((size_t)(base + row) << 6) + (tx << 2)) =
                make_float4(acc[rr][0], acc[rr][1], acc[rr][2], acc[rr][3]);
    }
}

// ---------------- gather-aggregate + self-loop + bias (+ LN + ReLU) ----------------
// float4 gather: 16 lanes x float4 cover one 256B row; 4 edges per VMEM instr.
template<bool LN>
__global__ void conv_kernel(const float* __restrict__ hw, const int* __restrict__ recs,
                            const int* __restrict__ cnt, const float* __restrict__ dinv,
                            const float* __restrict__ b, const float* __restrict__ g,
                            const float* __restrict__ be, float* __restrict__ out, int N) {
    int lane = threadIdx.x & 63;
    int row  = (blockIdx.x << 2) + (threadIdx.x >> 6);
    if (row >= N) return;

    int c = cnt[row];
    if (c > CAP) c = CAP;

    int s_l = 0; float ds_l = 0.f;     // masked slots contribute 0
    if (lane < c) { s_l = recs[(size_t)row * CAP + lane]; ds_l = dinv[s_l]; }

    int g4 = lane >> 4, j = lane & 15;
    const float4* hw4 = (const float4*)hw;
    float di = dinv[row];
    float4 self4 = hw4[(size_t)row * 16 + j];     // issue early

    float4 a0 = {0,0,0,0}, a1 = {0,0,0,0}, a2 = {0,0,0,0}, a3 = {0,0,0,0};
    int kmax = (c + 15) & ~15;
    for (int k = 0; k < kmax; k += 16) {
        int   s0 = __shfl(s_l, k + g4 + 0), s1 = __shfl(s_l, k + g4 + 4);
        int   s2 = __shfl(s_l, k + g4 + 8), s3 = __shfl(s_l, k + g4 + 12);
        float e0 = __shfl(ds_l, k + g4 + 0), e1 = __shfl(ds_l, k + g4 + 4);
        float e2 = __shfl(ds_l, k + g4 + 8), e3 = __shfl(ds_l, k + g4 + 12);
        float4 v0 = hw4[(size_t)s0 * 16 + j];
        float4 v1 = hw4[(size_t)s1 * 16 + j];
        float4 v2 = hw4[(size_t)s2 * 16 + j];
        float4 v3 = hw4[(size_t)s3 * 16 + j];
        a0.x = fmaf(e0, v0.x, a0.x); a0.y = fmaf(e0, v0.y, a0.y);
        a0.z = fmaf(e0, v0.z, a0.z); a0.w = fmaf(e0, v0.w, a0.w);
        a1.x = fmaf(e1, v1.x, a1.x); a1.y = fmaf(e1, v1.y, a1.y);
        a1.z = fmaf(e1, v1.z, a1.z); a1.w = fmaf(e1, v1.w, a1.w);
        a2.x = fmaf(e2, v2.x, a2.x); a2.y = fmaf(e2, v2.y, a2.y);
        a2.z = fmaf(e2, v2.z, a2.z); a2.w = fmaf(e2, v2.w, a2.w);
        a3.x = fmaf(e3, v3.x, a3.x); a3.y = fmaf(e3, v3.y, a3.y);
        a3.z = fmaf(e3, v3.z, a3.z); a3.w = fmaf(e3, v3.w, a3.w);
    }
    float4 acc;
    acc.x = (a0.x + a1.x) + (a2.x + a3.x);
    acc.y = (a0.y + a1.y) + (a2.y + a3.y);
    acc.z = (a0.z + a1.z) + (a2.z + a3.z);
    acc.w = (a0.w + a1.w) + (a2.w + a3.w);
    acc.x += __shfl_xor(acc.x, 16); acc.y += __shfl_xor(acc.y, 16);
    acc.z += __shfl_xor(acc.z, 16); acc.w += __shfl_xor(acc.w, 16);
    acc.x += __shfl_xor(acc.x, 32); acc.y += __shfl_xor(acc.y, 32);
    acc.z += __shfl_xor(acc.z, 32); acc.w += __shfl_xor(acc.w, 32);

    float4 b4 = ((const float4*)b)[j];
    float dd = di * di;
    acc.x = fmaf(di, acc.x, fmaf(dd, self4.x, b4.x));
    acc.y = fmaf(di, acc.y, fmaf(dd, self4.y, b4.y));
    acc.z = fmaf(di, acc.z, fmaf(dd, self4.z, b4.z));
    acc.w = fmaf(di, acc.w, fmaf(dd, self4.w, b4.w));

    if (LN) {
        float s = (acc.x + acc.y) + (acc.z + acc.w);
        #pragma unroll
        for (int o = 8; o; o >>= 1) s += __shfl_xor(s, o);
        float mu = s * (1.f / 64.f);
        float4 d0 = make_float4(acc.x - mu, acc.y - mu, acc.z - mu, acc.w - mu);
        float v = (d0.x * d0.x + d0.y * d0.y) + (d0.z * d0.z + d0.w * d0.w);
        #pragma unroll
        for (int o = 8; o; o >>= 1) v += __shfl_xor(v, o);
        float r = rsqrtf(v * (1.f / 64.f) + 1e-5f);
        float4 g4v = ((const float4*)g)[j];
        float4 be4 = ((const float4*)be)[j];
        acc.x = fmaxf(fmaf(d0.x * r, g4v.x, be4.x), 0.f);
        acc.y = fmaxf(fmaf(d0.y * r, g4v.y, be4.y), 0.f);
        acc.z = fmaxf(fmaf(d0.z * r, g4v.z, be4.z), 0.f);
        acc.w = fmaxf(fmaf(d0.w * r, g4v.w, be4.w), 0.f);
    }
    if (g4 == 0) ((float4*)out)[(size_t)row * 16 + j] = acc;
}

// ---------------- MLP (64->64 relu ->40) + softmax ----------------
__global__ __launch_bounds__(256) void mlp_kernel(const float* __restrict__ h,
                           const float* __restrict__ M1, const float* __restrict__ mb1,
                           const float* __restrict__ M2, const float* __restrict__ mb2,
                           float* __restrict__ out, int N) {
    __shared__ float Hs [64][68];
    __shared__ float W1s[64][68];
    __shared__ float H2s[64][68];
    __shared__ float W2s[64][44];
    int tid = threadIdx.x;
    int base = blockIdx.x << 6;
    int rows = N - base; if (rows > 64) rows = 64;

    {   // stage M1
        int k = tid >> 4, c = (tid & 15) << 2;
        #pragma unroll
        for (int k0 = 0; k0 < 64; k0 += 16) {
            float4 wv = *(const float4*)(M1 + (size_t)((k0 + k) << 6) + c);
            *(float4*)&W1s[k0 + k][c] = wv;
        }
    }
    for (int i = tid; i < 64 * OUTC; i += 256)
        W2s[i / OUTC][i % OUTC] = M2[i];
    {   // stage h transposed
        int r = tid >> 2, q = (tid & 3) << 2;
        int rc = r < rows ? r : 0;
        const float* xp = h + (((size_t)(base + rc)) << 6) + q;
        #pragma unroll
        for (int k0 = 0; k0 < 64; k0 += 16) {
            float4 xv = *(const float4*)(xp + k0);
            Hs[k0 + q + 0][r] = xv.x;
            Hs[k0 + q + 1][r] = xv.y;
            Hs[k0 + q + 2][r] = xv.z;
            Hs[k0 + q + 3][r] = xv.w;
        }
    }
    __syncthreads();

    int tx = tid & 15, ty = tid >> 4;

    float acc[4][4] = {};
    #pragma unroll 4
    for (int k = 0; k < 64; k++) {
        float4 a = *(const float4*)&Hs[k][ty << 2];
        float4 b = *(const float4*)&W1s[k][tx << 2];
        FMA16(acc, a, b)
    }
    float4 b1v = *(const float4*)(mb1 + (tx << 2));
    #pragma unroll
    for (int cc = 0; cc < 4; cc++) {
        float bc = cc == 0 ? b1v.x : cc == 1 ? b1v.y : cc == 2 ? b1v.z : b1v.w;
        #pragma unroll
        for (int rr = 0; rr < 4; rr++)
            H2s[(tx << 2) + cc][(ty << 2) + rr] = fmaxf(acc[rr][cc] + bc, 0.f);
    }
    __syncthreads();

    int bx = (tx < 10) ? (tx << 2) : 0;
    float acc2[4][4] = {};
    #pragma unroll 4
    for (int k = 0; k < 64; k++) {
        float4 a = *(const float4*)&H2s[k][ty << 2];
        float4 b = *(const float4*)&W2s[k][bx];
        FMA16(acc2, a, b)
    }
    float4 b2v = *(const float4*)(mb2 + bx);

    #pragma unroll
    for (int rr = 0; rr < 4; rr++) {
        float v0 = acc2[rr][0] + b2v.x, v1 = acc2[rr][1] + b2v.y;
        float v2 = acc2[rr][2] + b2v.z, v3 = acc2[rr][3] + b2v.w;
        float m = fmaxf(fmaxf(v0, v1), fmaxf(v2, v3));
        if (tx >= 10) m = -1e30f;
        #pragma unroll
        for (int s = 1; s < 16; s <<= 1) m = fmaxf(m, __shfl_xor(m, s));
        float e0 = __expf(v0 - m), e1 = __expf(v1 - m);
        float e2 = __expf(v2 - m), e3 = __expf(v3 - m);
        float sum = (tx < 10) ? (e0 + e1) + (e2 + e3) : 0.f;
        #pragma unroll
        for (int s = 1; s < 16; s <<= 1) sum += __shfl_xor(sum, s);
        float inv = 1.f / sum;
        int row = (ty << 2) + rr;
        if (tx < 10 && row < rows)
            *(float4*)(out + (size_t)(base + row) * OUTC + bx) =
                make_float4(e0 * inv, e1 * inv, e2 * inv, e3 * inv);
    }
}

extern "C" void kernel_launch(void* const* d_in, const int* in_sizes, int n_in,
                              void* d_out, int out_size, void* d_ws, size_t ws_size,
                              hipStream_t stream) {
    const float* x   = (const float*)d_in[0];
    const int*   ei  = (const int*)  d_in[1];
    const float* W1  = (const float*)d_in[2];
    const float* b1  = (const float*)d_in[3];
    const float* W2  = (const float*)d_in[4];
    const float* b2  = (const float*)d_in[5];
    const float* W3  = (const float*)d_in[6];
    const float* b3  = (const float*)d_in[7];
    const float* g1  = (const float*)d_in[8];
    const float* be1 = (const float*)d_in[9];
    const float* g2  = (const float*)d_in[10];
    const float* be2 = (const float*)d_in[11];
    const float* M1  = (const float*)d_in[12];
    const float* mb1 = (const float*)d_in[13];
    const float* M2  = (const float*)d_in[14];
    const float* mb2 = (const float*)d_in[15];

    const int IN_C = 128;
    int N = in_sizes[0] / IN_C;
    int E = in_sizes[1] / 2;
    const int* src = ei;
    const int* dst = ei + E;

    char* ws = (char*)d_ws;
    size_t off = 0;
    auto carve = [&](size_t bytes) -> void* {
        void* p = ws + off;
        off = (off + bytes + 255) & ~(size_t)255;
        return p;
    };
    int*   cnt  = (int*)  carve(((size_t)N + 4) * sizeof(int));  // padded to int4
    float* dinv = (float*)carve((size_t)N * sizeof(float));
    int*   recs = (int*)  carve((size_t)N * CAP * sizeof(int));
    float* HW   = (float*)carve((size_t)N * HID * sizeof(float));
    float* H    = (float*)carve((size_t)N * HID * sizeof(float));

    int n4 = (N + 3) / 4;
    zero_kernel<<<(n4 + 255) / 256, 256, 0, stream>>>((int4*)cnt, n4);

    int nb = (N + 255) / 256;
    int rb = (N + 3) / 4;    // conv: one wave per node, 4 waves/block
    int tb = (N + 63) / 64;  // xform/mlp: 64-row tile per 256-thread block

    fill_kernel<<<2048, 256, 0, stream>>>(src, dst, cnt, recs, E, N);
    dinv_kernel<<<nb, 256, 0, stream>>>(cnt, dinv, N);

    // layer 1
    xform_kernel<128><<<tb, 256, 0, stream>>>(x, W1, HW, N);
    conv_kernel<true><<<rb, 256, 0, stream>>>(HW, recs, cnt, dinv, b1, g1, be1, H, N);
    // layer 2
    xform_kernel<64><<<tb, 256, 0, stream>>>(H, W2, HW, N);
    conv_kernel<true><<<rb, 256, 0, stream>>>(HW, recs, cnt, dinv, b2, g2, be2, H, N);
    // layer 3 (no LN/ReLU)
    xform_kernel<64><<<tb, 256, 0, stream>>>(H, W3, HW, N);
    conv_kernel<false><<<rb, 256, 0, stream>>>(HW, recs, cnt, dinv, b3, nullptr, nullptr, H, N);

    // MLP + softmax
    mlp_kernel<<<tb, 256, 0, stream>>>(H, M1, mb1, M2, mb2, (float*)d_out, N);
}